// Round 15
// baseline (398.700 us; speedup 1.0000x reference)
//
#include <hip/hip_runtime.h>

#define TE 64      // edges per tile
#define TN 64      // nodes per tile
#define HISTB 2048 // hist blocks inside prep kernel

union F4 { float4 v; float f[4]; };
typedef unsigned long long u64;

__device__ __forceinline__ float gelu_f(float x) {
    // jax.nn.gelu(approximate=True): 0.5*x*(1+tanh(sqrt(2/pi)*(x+0.044715*x^3)))
    const float c0 = 0.7978845608028654f;
    float z = c0 * (x + 0.044715f * x * x * x);
    float ez = __builtin_exp2f(z * 2.8853900817779268f);
    float th = 1.0f - 2.0f * __builtin_amdgcn_rcpf(ez + 1.0f);
    return 0.5f * x * (1.0f + th);
}

__device__ __forceinline__ void barrier_lgkm() {
    asm volatile("s_waitcnt lgkmcnt(0)" ::: "memory");
    __builtin_amdgcn_s_barrier();
}

// ---------------- Edge kernel (r9/r13 structure — measured 188us; UNCHANGED) ----------------
__global__ __launch_bounds__(256, 6) void edge_np_kernel(
    const float* __restrict__ ef,   // [E,16]
    const u64*   __restrict__ esd,  // [E] packed src|dst<<17|eid<<34, dst-sorted
    const float* __restrict__ np,   // [N,64] nodePart = nf@W1[0:64]
    const float* __restrict__ W1,   // [80,64]
    const float* __restrict__ b1,   // [64]
    float*       __restrict__ gsum, // [N,64] pre-zeroed
    int nE, int nTiles)
{
    __shared__ float sX[16][TE + 4];   // ef transposed [k][e]
    __shared__ float sM[64][TE + 4];   // gelu(msg1) transposed [c][e]
    __shared__ int   sDst[TE];
    __shared__ int   sSrc[TE];

    const int t    = threadIdx.x;
    const int lane = t & 63;
    const int w    = t >> 6;          // wave id 0..3
    const int e0   = (t & 15) * 4;    // microtile edges
    const int c0   = (t >> 4) * 4;    // microtile channels
    F4 b1v;
    b1v.v = *(const float4*)(b1 + c0);

    for (int tile = blockIdx.x; tile < nTiles; tile += gridDim.x) {
        const int gbase = tile * TE;
        // ---- gather: lane = edge, wave = 4-feature chunk ----
        {
            const int idx = gbase + lane;
            const int ci  = idx < nE ? idx : nE - 1;    // clamp (tail-safe)
            const u64 e   = esd[ci];
            const int src = (int)(e & 0x1FFFF);
            const int dst = (int)((e >> 17) & 0x1FFFF);
            const int ge  = (int)(e >> 34);
            F4 ev;
            ev.v = *(const float4*)(ef + (size_t)ge * 16 + w * 4);
            #pragma unroll
            for (int j = 0; j < 4; ++j)
                sX[w * 4 + j][lane] = ev.f[j];
            if (w == 0) sDst[lane] = (idx < nE) ? dst : -1;   // sentinel pad
            if (w == 1) sSrc[lane] = src;
        }
        barrier_lgkm();

        // ---- GEMM1 (16 k-iters) + np[src] add ----
        float acc[4][4] = {};
        #pragma unroll
        for (int k = 0; k < 16; ++k) {
            F4 xv, wv;
            xv.v = *(const float4*)&sX[k][e0];
            wv.v = *(const float4*)(W1 + (64 + k) * 64 + c0);
            #pragma unroll
            for (int i = 0; i < 4; ++i)
                #pragma unroll
                for (int j = 0; j < 4; ++j)
                    acc[i][j] = fmaf(xv.f[i], wv.f[j], acc[i][j]);
        }
        #pragma unroll
        for (int i = 0; i < 4; ++i) {
            F4 npv;
            npv.v = *(const float4*)(np + (size_t)sSrc[e0 + i] * 64 + c0);
            #pragma unroll
            for (int j = 0; j < 4; ++j)
                acc[i][j] += npv.f[j];
        }

        // gelu + write transposed
        #pragma unroll
        for (int j = 0; j < 4; ++j) {
            F4 col;
            #pragma unroll
            for (int i = 0; i < 4; ++i)
                col.f[i] = gelu_f(acc[i][j] + b1v.f[j]);
            *(float4*)&sM[c0 + j][e0] = col.v;
        }
        barrier_lgkm();

        // ---- segmented reduction along sorted-edge axis ----
        const int c  = t >> 2;
        const int q  = t & 3;
        const int cb = q * 16;
        int   cur = -1;
        float run = 0.f;
        #pragma unroll
        for (int s = 0; s < 4; ++s) {
            F4 rv;
            rv.v = *(const float4*)&sM[c][cb + s * 4];
            #pragma unroll
            for (int j = 0; j < 4; ++j) {
                const int d = sDst[cb + s * 4 + j];
                if (d != cur) {
                    if (cur >= 0)
                        __hip_atomic_fetch_add(gsum + (size_t)cur * 64 + c, run,
                                               __ATOMIC_RELAXED, __HIP_MEMORY_SCOPE_AGENT);
                    cur = d;
                    run = 0.f;
                }
                if (d >= 0) run += rv.f[j];
            }
        }
        if (cur >= 0)
            __hip_atomic_fetch_add(gsum + (size_t)cur * 64 + c, run,
                                   __ATOMIC_RELAXED, __HIP_MEMORY_SCOPE_AGENT);
        barrier_lgkm();   // protect sM/sDst/sSrc before next gather
    }
}

// ---------------- fused prep: node_part (blocks<gridB) | hist | W23 (last block) ----------------
__global__ __launch_bounds__(256) void prep_kernel(
    const float* __restrict__ nf, const float* __restrict__ W1,
    const int* __restrict__ ei, int nE, int nN, int gridB,
    float* __restrict__ np, float* __restrict__ gz, int* __restrict__ counts,
    const float* __restrict__ W2, const float* __restrict__ W3, const float* __restrict__ b2,
    float* __restrict__ W23, float* __restrict__ b2w)
{
    __shared__ float sU[64][TN + 4];
    const int t = threadIdx.x;
    const int b = blockIdx.x;

    if (b >= gridB + HISTB) {
        // ---- W23 = W2 @ W3[64:128,:]; b2w = b2 @ W3[64:128,:] ----
        const int c = t & 63;
        const int kg = t >> 6;
        for (int k = kg * 16; k < kg * 16 + 16; ++k) {
            float s = 0.f;
            for (int m = 0; m < 64; ++m)
                s = fmaf(W2[k * 64 + m], W3[(64 + m) * 64 + c], s);
            W23[k * 64 + c] = s;
        }
        if (t < 64) {
            float s = 0.f;
            for (int m = 0; m < 64; ++m)
                s = fmaf(b2[m], W3[(64 + m) * 64 + t], s);
            b2w[t] = s;
        }
        return;
    }
    if (b >= gridB) {
        // ---- histogram of dst (counts pre-zeroed by memset) ----
        const int* dst = ei + nE;
        int e = (b - gridB) * 256 + t;
        const int stride = HISTB * 256;
        for (; e < nE; e += stride)
            atomicAdd(&counts[dst[e]], 1);
        return;
    }

    // ---- node_part: npart = nf @ W1[0:64,:]; zero gsum rows ----
    const int lane = t & 63;
    const int w = t >> 6;
    const int tb = b * TN;
    const int node = (tb + lane < nN) ? tb + lane : nN - 1;
    {
        const float4 z = make_float4(0.f, 0.f, 0.f, 0.f);
        const int base = tb * 64 + t * 4;
        #pragma unroll
        for (int pz = 0; pz < 4; ++pz) {
            const int idx = base + pz * 1024;
            if (idx < nN * 64) *(float4*)(gz + idx) = z;
        }
    }
    {
        const float4* nrow = (const float4*)(nf + (size_t)node * 64);
        F4 a0, a1, a2, a3;
        a0.v = nrow[w * 4 + 0];
        a1.v = nrow[w * 4 + 1];
        a2.v = nrow[w * 4 + 2];
        a3.v = nrow[w * 4 + 3];
        const int kb = w * 16;
        #pragma unroll
        for (int j = 0; j < 4; ++j) {
            sU[kb + 0  + j][lane] = a0.f[j];
            sU[kb + 4  + j][lane] = a1.f[j];
            sU[kb + 8  + j][lane] = a2.f[j];
            sU[kb + 12 + j][lane] = a3.f[j];
        }
    }
    barrier_lgkm();
    const int n0 = (t & 15) * 4;
    const int c0 = (t >> 4) * 4;
    float acc[4][4] = {};
    #pragma unroll 8
    for (int k = 0; k < 64; ++k) {
        F4 xv, wv;
        xv.v = *(const float4*)&sU[k][n0];
        wv.v = *(const float4*)(W1 + k * 64 + c0);
        #pragma unroll
        for (int i = 0; i < 4; ++i)
            #pragma unroll
            for (int j = 0; j < 4; ++j)
                acc[i][j] = fmaf(xv.f[i], wv.f[j], acc[i][j]);
    }
    #pragma unroll
    for (int i = 0; i < 4; ++i) {
        const int gnode = tb + n0 + i;
        if (gnode < nN) {
            F4 o;
            #pragma unroll
            for (int j = 0; j < 4; ++j) o.f[j] = acc[i][j];
            *(float4*)(np + (size_t)gnode * 64 + c0) = o.v;
        }
    }
}

// ---------------- scan chain (bsum scan folded into scan_add) ----------------
__global__ __launch_bounds__(256) void scan_local_kernel(const int* __restrict__ in,
                                                         int* __restrict__ out,
                                                         int* __restrict__ bsum, int n) {
    __shared__ int s[256];
    const int t = threadIdx.x;
    const int base = blockIdx.x * 2048 + t * 8;
    int v[8];
    #pragma unroll
    for (int i = 0; i < 8; ++i) v[i] = (base + i < n) ? in[base + i] : 0;
    int run = 0;
    #pragma unroll
    for (int i = 0; i < 8; ++i) { int c = v[i]; v[i] = run; run += c; }
    s[t] = run;
    __syncthreads();
    int x = run;
    for (int off = 1; off < 256; off <<= 1) {
        int y = (t >= off) ? s[t - off] : 0;
        __syncthreads();
        x += y; s[t] = x;
        __syncthreads();
    }
    const int texcl = x - run;
    if (t == 255) bsum[blockIdx.x] = x;
    #pragma unroll
    for (int i = 0; i < 8; ++i)
        if (base + i < n) out[base + i] = texcl + v[i];
}

// each block redundantly scans raw bsum (nb<=64: one wave shfl pass) -> its own prefix
__global__ __launch_bounds__(256) void scan_add_kernel(int* __restrict__ offs,
                                                       const int* __restrict__ bsum, int nb,
                                                       int* __restrict__ cursor, int n) {
    __shared__ int sAdd;
    const int t = threadIdx.x;
    if (t < 64) {
        int add = 0;
        if (nb <= 64) {
            int v = (t < nb) ? bsum[t] : 0;
            for (int off = 1; off < 64; off <<= 1) {
                int y = __shfl_up(v, off, 64);
                if (t >= off) v += y;
            }
            // exclusive prefix for this block = inclusive[blockIdx.x - 1]
            int excl = __shfl(v, blockIdx.x - 1, 64);
            add = (blockIdx.x == 0) ? 0 : excl;
        } else if (t == 0) {
            for (int i = 0; i < (int)blockIdx.x && i < nb; ++i) add += bsum[i];
        }
        if (t == 0) sAdd = add;
        if (nb <= 64 && t == (int)(blockIdx.x & 63)) { /* keep wave converged */ }
    }
    __syncthreads();
    const int add = sAdd;
    const int base = blockIdx.x * 2048 + t * 8;
    #pragma unroll
    for (int i = 0; i < 8; ++i)
        if (base + i < n) { int v = offs[base + i] + add; offs[base + i] = v; cursor[base + i] = v; }
}

__global__ __launch_bounds__(256) void scatter_kernel(const int* __restrict__ ei,
                                                      int* __restrict__ cursor,
                                                      u64* __restrict__ esd, int nE) {
    int e = blockIdx.x * 256 + threadIdx.x;
    const int stride = gridDim.x * 256;
    for (; e < nE; e += stride) {
        const int s = ei[e];
        const int d = ei[nE + e];
        const int pos = atomicAdd(&cursor[d], 1);
        esd[pos] = (u64)(unsigned)s | ((u64)(unsigned)d << 17) | ((u64)(unsigned)e << 34);
    }
}

// ---------------- Fallback edge kernel (block-tile, full GEMM1+GEMM2+atomics) ----------------
__global__ __launch_bounds__(256, 4) void edge_mlp_kernel(
    const float* __restrict__ nf, const float* __restrict__ ef,
    const int* __restrict__ ei,
    const float* __restrict__ W1, const float* __restrict__ b1,
    const float* __restrict__ W2, const float* __restrict__ b2,
    float* agg, int nE, int nTiles)
{
    __shared__ float sX[80][TE + 4];
    __shared__ float sM[64][TE + 4];
    __shared__ int   sDst[TE];

    const int t    = threadIdx.x;
    const int lane = t & 63;
    const int w    = t >> 6;
    const int e0   = (t & 15) * 4;
    const int c0   = (t >> 4) * 4;
    F4 b1v, b2v;
    b1v.v = *(const float4*)(b1 + c0);
    b2v.v = *(const float4*)(b2 + c0);

    for (int tile = blockIdx.x; tile < nTiles; tile += gridDim.x) {
        const int gbase = tile * TE;
        {
            const int idx = gbase + lane;
            const int ge  = idx < nE ? idx : nE - 1;
            const int src = ei[ge];
            const int dstv = (idx < nE) ? ei[nE + ge] : -1;
            const float4* nrow = (const float4*)(nf + (size_t)src * 64);
            F4 a0, a1, a2, a3, ev;
            a0.v = nrow[w * 4 + 0];
            a1.v = nrow[w * 4 + 1];
            a2.v = nrow[w * 4 + 2];
            a3.v = nrow[w * 4 + 3];
            ev.v = *(const float4*)(ef + (size_t)ge * 16 + w * 4);
            const int kb = w * 16;
            #pragma unroll
            for (int j = 0; j < 4; ++j) {
                sX[kb + 0  + j][lane] = a0.f[j];
                sX[kb + 4  + j][lane] = a1.f[j];
                sX[kb + 8  + j][lane] = a2.f[j];
                sX[kb + 12 + j][lane] = a3.f[j];
                sX[64 + w * 4 + j][lane] = ev.f[j];
            }
            if (w == 0) sDst[lane] = dstv;
        }
        barrier_lgkm();

        float acc[4][4] = {};
        #pragma unroll 8
        for (int k = 0; k < 80; ++k) {
            F4 xv, wv;
            xv.v = *(const float4*)&sX[k][e0];
            wv.v = *(const float4*)(W1 + k * 64 + c0);
            #pragma unroll
            for (int i = 0; i < 4; ++i)
                #pragma unroll
                for (int j = 0; j < 4; ++j)
                    acc[i][j] = fmaf(xv.f[i], wv.f[j], acc[i][j]);
        }
        #pragma unroll
        for (int j = 0; j < 4; ++j) {
            F4 col;
            #pragma unroll
            for (int i = 0; i < 4; ++i)
                col.f[i] = gelu_f(acc[i][j] + b1v.f[j]);
            *(float4*)&sM[c0 + j][e0] = col.v;
        }
        barrier_lgkm();

        float acc2[4][4] = {};
        #pragma unroll 8
        for (int k = 0; k < 64; ++k) {
            F4 xv, wv;
            xv.v = *(const float4*)&sM[k][e0];
            wv.v = *(const float4*)(W2 + k * 64 + c0);
            #pragma unroll
            for (int i = 0; i < 4; ++i)
                #pragma unroll
                for (int j = 0; j < 4; ++j)
                    acc2[i][j] = fmaf(xv.f[i], wv.f[j], acc2[i][j]);
        }
        #pragma unroll
        for (int i = 0; i < 4; ++i) {
            if (gbase + e0 + i < nE) {
                float* arow = agg + (size_t)sDst[e0 + i] * 64 + c0;
                #pragma unroll
                for (int j = 0; j < 4; ++j)
                    __hip_atomic_fetch_add(arow + j, acc2[i][j] + b2v.f[j],
                                           __ATOMIC_RELAXED, __HIP_MEMORY_SCOPE_AGENT);
            }
        }
        barrier_lgkm();
    }
}

// ---------------- Kernel B: node update + LN + GELU + residual (W3 streamed from L1) ----------------
__global__ __launch_bounds__(256) void node_update_kernel(
    const float* __restrict__ nf,
    const float* gsum,               // may alias out
    const float* __restrict__ W3,    // rows 0..63
    const float* __restrict__ wB,    // rows 64..127 (W23 or W3+4096)
    const float* __restrict__ b3,
    const float* __restrict__ cvec,  // b2w or null
    const int*   __restrict__ counts,// [N] or null
    const float* __restrict__ lns,
    const float* __restrict__ lnb,
    float* out, int nN)
{
    __shared__ float sU[128][TN + 4];
    __shared__ float sP1[16][TN];
    __shared__ float sP2[16][TN];
    __shared__ float sMu[TN];
    __shared__ float sRs[TN];

    const int t = threadIdx.x;
    const int lane = t & 63;
    const int w    = t >> 6;
    const int tb   = blockIdx.x * TN;
    const int node = tb + lane;
    const bool valid = node < nN;

    {
        const float* base = (w < 2) ? (nf   + (size_t)node * 64 + w * 32)
                                    : (gsum + (size_t)node * 64 + (w - 2) * 32);
        const int kb = (w < 2) ? (w * 32) : (64 + (w - 2) * 32);
        #pragma unroll
        for (int q = 0; q < 8; ++q) {
            F4 v;
            v.v = valid ? *(const float4*)(base + q * 4) : make_float4(0.f, 0.f, 0.f, 0.f);
            #pragma unroll
            for (int j = 0; j < 4; ++j)
                sU[kb + q * 4 + j][lane] = v.f[j];
        }
    }

    const int n0 = (t & 15) * 4;
    const int c0 = (t >> 4) * 4;
    F4 b3v, sv, bv, cv;
    b3v.v = *(const float4*)(b3  + c0);
    sv.v  = *(const float4*)(lns + c0);
    bv.v  = *(const float4*)(lnb + c0);
    if (cvec) cv.v = *(const float4*)(cvec + c0);
    __syncthreads();

    float acc[4][4] = {};
    #pragma unroll 8
    for (int k = 0; k < 64; ++k) {
        F4 xv, wv;
        xv.v = *(const float4*)&sU[k][n0];
        wv.v = *(const float4*)(W3 + k * 64 + c0);   // streamed, L1-resident
        #pragma unroll
        for (int i = 0; i < 4; ++i)
            #pragma unroll
            for (int j = 0; j < 4; ++j)
                acc[i][j] = fmaf(xv.f[i], wv.f[j], acc[i][j]);
    }
    #pragma unroll 8
    for (int k = 0; k < 64; ++k) {
        F4 xv, wv;
        xv.v = *(const float4*)&sU[64 + k][n0];
        wv.v = *(const float4*)(wB + k * 64 + c0);   // streamed, L1-resident
        #pragma unroll
        for (int i = 0; i < 4; ++i)
            #pragma unroll
            for (int j = 0; j < 4; ++j)
                acc[i][j] = fmaf(xv.f[i], wv.f[j], acc[i][j]);
    }

    float h[4][4];
    #pragma unroll
    for (int i = 0; i < 4; ++i) {
        float cf = 0.f;
        if (counts) {
            const int gnode = tb + n0 + i;
            cf = (float)counts[gnode < nN ? gnode : nN - 1];
        }
        #pragma unroll
        for (int j = 0; j < 4; ++j) {
            float v = acc[i][j] + b3v.f[j];
            if (cvec) v = fmaf(cf, cv.f[j], v);
            h[i][j] = v;
        }
    }

    const int cg = t >> 4;
    #pragma unroll
    for (int i = 0; i < 4; ++i) {
        float s1 = h[i][0] + h[i][1] + h[i][2] + h[i][3];
        float s2 = h[i][0]*h[i][0] + h[i][1]*h[i][1] + h[i][2]*h[i][2] + h[i][3]*h[i][3];
        sP1[cg][n0 + i] = s1;
        sP2[cg][n0 + i] = s2;
    }
    __syncthreads();
    if (t < TN) {
        float m1 = 0.f, m2 = 0.f;
        #pragma unroll
        for (int g = 0; g < 16; ++g) { m1 += sP1[g][t]; m2 += sP2[g][t]; }
        float mu  = m1 * (1.f / 64.f);
        float var = m2 * (1.f / 64.f) - mu * mu;
        sMu[t] = mu;
        sRs[t] = rsqrtf(var + 1e-6f);
    }
    __syncthreads();

    #pragma unroll
    for (int i = 0; i < 4; ++i) {
        const int gnode = tb + n0 + i;
        const float mu = sMu[n0 + i];
        const float rs = sRs[n0 + i];
        if (gnode < nN) {
            #pragma unroll
            for (int j = 0; j < 4; ++j) {
                float xn = (h[i][j] - mu) * rs * sv.f[j] + bv.f[j];
                float r  = gelu_f(xn) + sU[c0 + j][n0 + i];
                out[(size_t)gnode * 64 + c0 + j] = r;
            }
        }
    }
}

extern "C" void kernel_launch(void* const* d_in, const int* in_sizes, int n_in,
                              void* d_out, int out_size, void* d_ws, size_t ws_size,
                              hipStream_t stream)
{
    const float* nf  = (const float*)d_in[0];
    const float* ef  = (const float*)d_in[1];
    const int*   ei  = (const int*)  d_in[2];
    const float* W1  = (const float*)d_in[3];
    const float* b1  = (const float*)d_in[4];
    const float* W2  = (const float*)d_in[5];
    const float* b2  = (const float*)d_in[6];
    const float* W3  = (const float*)d_in[7];
    const float* b3  = (const float*)d_in[8];
    const float* lns = (const float*)d_in[9];
    const float* lnb = (const float*)d_in[10];

    const int nN = in_sizes[0] / 64;
    const int nE = in_sizes[2] / 2;
    float* out = (float*)d_out;

    const int gridB = (nN + TN - 1) / TN;
    const int nTiles = (nE + TE - 1) / TE;

    // ws layout: CSR + folded weights -> nodePart -> gSum
    char* ws = (char*)d_ws;
    size_t off = 0;
    auto take = [&](size_t bytes) { void* p = ws + off; off = (off + bytes + 255) & ~(size_t)255; return p; };
    int*   counts = (int*)  take((size_t)nN * 4);
    int*   offs   = (int*)  take((size_t)nN * 4);
    int*   cursor = (int*)  take((size_t)nN * 4);
    int*   bsum   = (int*)  take(4096);
    u64*   esd    = (u64*)  take((size_t)nE * 8);
    float* W23    = (float*)take(64 * 64 * 4);
    float* b2w    = (float*)take(64 * 4);
    float* npart  = (float*)take((size_t)nN * 64 * 4);
    const size_t tier2End = off;
    float* gsumw  = (float*)take((size_t)nN * 64 * 4);
    const size_t tier3End = off;
    const size_t aggBytes = (size_t)nN * 64 * 4;
    const bool fitsPacked = (nN <= (1 << 17)) && (nE <= (1 << 21));

    if (ws_size >= tier2End && fitsPacked) {
        // ---- fast path: fused prep + 2-launch scan + scatter + r13 edge kernel ----
        float* gsum = (ws_size >= tier3End) ? gsumw : out;  // aliasing out is safe (block-local RAW)
        const int nb = (nN + 2047) / 2048;
        hipMemsetAsync(counts, 0, (size_t)nN * 4, stream);
        hipLaunchKernelGGL(prep_kernel, dim3(gridB + HISTB + 1), dim3(256), 0, stream,
                           nf, W1, ei, nE, nN, gridB, npart, gsum, counts,
                           W2, W3, b2, W23, b2w);
        hipLaunchKernelGGL(scan_local_kernel, dim3(nb), dim3(256), 0, stream, counts, offs, bsum, nN);
        hipLaunchKernelGGL(scan_add_kernel, dim3(nb), dim3(256), 0, stream, offs, bsum, nb, cursor, nN);
        hipLaunchKernelGGL(scatter_kernel, dim3(2048), dim3(256), 0, stream, ei, cursor, esd, nE);

        const int gridE = nTiles < 1536 ? nTiles : 1536;   // 6 blocks/CU resident (22.5KB LDS)
        hipLaunchKernelGGL(edge_np_kernel, dim3(gridE), dim3(256), 0, stream,
                           ef, esd, npart, W1, b1, gsum, nE, nTiles);

        hipLaunchKernelGGL(node_update_kernel, dim3(gridB), dim3(256), 0, stream,
                           nf, gsum, W3, W23, b3, b2w, counts, lns, lnb, out, nN);
    } else {
        // ---- fallback: block-tile edge kernel with per-edge atomics ----
        const int gridA = nTiles < 1024 ? nTiles : 1024;
        float* agg = (ws_size >= aggBytes) ? (float*)d_ws : out;
        hipMemsetAsync(agg, 0, aggBytes, stream);
        hipLaunchKernelGGL(edge_mlp_kernel, dim3(gridA), dim3(256), 0, stream,
                           nf, ef, ei, W1, b1, W2, b2, agg, nE, nTiles);
        hipLaunchKernelGGL(node_update_kernel, dim3(gridB), dim3(256), 0, stream,
                           nf, agg, W3, W3 + 64 * 64, b3, (const float*)nullptr, (const int*)nullptr,
                           lns, lnb, out, nN);
    }
}

// Round 16
// 379.086 us; speedup vs baseline: 1.0517x; 1.0517x over previous
//
#include <hip/hip_runtime.h>

#define TE 64      // edges per tile
#define TN 64      // nodes per tile
#define HISTB 2048 // hist blocks inside prep kernel

union F4 { float4 v; float f[4]; };
typedef unsigned long long u64;

__device__ __forceinline__ float gelu_f(float x) {
    // jax.nn.gelu(approximate=True): 0.5*x*(1+tanh(sqrt(2/pi)*(x+0.044715*x^3)))
    const float c0 = 0.7978845608028654f;
    float z = c0 * (x + 0.044715f * x * x * x);
    float ez = __builtin_exp2f(z * 2.8853900817779268f);
    float th = 1.0f - 2.0f * __builtin_amdgcn_rcpf(ez + 1.0f);
    return 0.5f * x * (1.0f + th);
}

__device__ __forceinline__ void barrier_lgkm() {
    asm volatile("s_waitcnt lgkmcnt(0)" ::: "memory");
    __builtin_amdgcn_s_barrier();
}

// ---------------- Edge kernel (r9/r13 structure — measured 188us; UNCHANGED) ----------------
__global__ __launch_bounds__(256, 6) void edge_np_kernel(
    const float* __restrict__ ef,   // [E,16]
    const u64*   __restrict__ esd,  // [E] packed src|dst<<17|eid<<34, dst-sorted
    const float* __restrict__ np,   // [N,64] nodePart = nf@W1[0:64]
    const float* __restrict__ W1,   // [80,64]
    const float* __restrict__ b1,   // [64]
    float*       __restrict__ gsum, // [N,64] pre-zeroed
    int nE, int nTiles)
{
    __shared__ float sX[16][TE + 4];   // ef transposed [k][e]
    __shared__ float sM[64][TE + 4];   // gelu(msg1) transposed [c][e]
    __shared__ int   sDst[TE];
    __shared__ int   sSrc[TE];

    const int t    = threadIdx.x;
    const int lane = t & 63;
    const int w    = t >> 6;          // wave id 0..3
    const int e0   = (t & 15) * 4;    // microtile edges
    const int c0   = (t >> 4) * 4;    // microtile channels
    F4 b1v;
    b1v.v = *(const float4*)(b1 + c0);

    for (int tile = blockIdx.x; tile < nTiles; tile += gridDim.x) {
        const int gbase = tile * TE;
        // ---- gather: lane = edge, wave = 4-feature chunk ----
        {
            const int idx = gbase + lane;
            const int ci  = idx < nE ? idx : nE - 1;    // clamp (tail-safe)
            const u64 e   = esd[ci];
            const int src = (int)(e & 0x1FFFF);
            const int dst = (int)((e >> 17) & 0x1FFFF);
            const int ge  = (int)(e >> 34);
            F4 ev;
            ev.v = *(const float4*)(ef + (size_t)ge * 16 + w * 4);
            #pragma unroll
            for (int j = 0; j < 4; ++j)
                sX[w * 4 + j][lane] = ev.f[j];
            if (w == 0) sDst[lane] = (idx < nE) ? dst : -1;   // sentinel pad
            if (w == 1) sSrc[lane] = src;
        }
        barrier_lgkm();

        // ---- GEMM1 (16 k-iters) + np[src] add ----
        float acc[4][4] = {};
        #pragma unroll
        for (int k = 0; k < 16; ++k) {
            F4 xv, wv;
            xv.v = *(const float4*)&sX[k][e0];
            wv.v = *(const float4*)(W1 + (64 + k) * 64 + c0);
            #pragma unroll
            for (int i = 0; i < 4; ++i)
                #pragma unroll
                for (int j = 0; j < 4; ++j)
                    acc[i][j] = fmaf(xv.f[i], wv.f[j], acc[i][j]);
        }
        #pragma unroll
        for (int i = 0; i < 4; ++i) {
            F4 npv;
            npv.v = *(const float4*)(np + (size_t)sSrc[e0 + i] * 64 + c0);
            #pragma unroll
            for (int j = 0; j < 4; ++j)
                acc[i][j] += npv.f[j];
        }

        // gelu + write transposed
        #pragma unroll
        for (int j = 0; j < 4; ++j) {
            F4 col;
            #pragma unroll
            for (int i = 0; i < 4; ++i)
                col.f[i] = gelu_f(acc[i][j] + b1v.f[j]);
            *(float4*)&sM[c0 + j][e0] = col.v;
        }
        barrier_lgkm();

        // ---- segmented reduction along sorted-edge axis ----
        const int c  = t >> 2;
        const int q  = t & 3;
        const int cb = q * 16;
        int   cur = -1;
        float run = 0.f;
        #pragma unroll
        for (int s = 0; s < 4; ++s) {
            F4 rv;
            rv.v = *(const float4*)&sM[c][cb + s * 4];
            #pragma unroll
            for (int j = 0; j < 4; ++j) {
                const int d = sDst[cb + s * 4 + j];
                if (d != cur) {
                    if (cur >= 0)
                        __hip_atomic_fetch_add(gsum + (size_t)cur * 64 + c, run,
                                               __ATOMIC_RELAXED, __HIP_MEMORY_SCOPE_AGENT);
                    cur = d;
                    run = 0.f;
                }
                if (d >= 0) run += rv.f[j];
            }
        }
        if (cur >= 0)
            __hip_atomic_fetch_add(gsum + (size_t)cur * 64 + c, run,
                                   __ATOMIC_RELAXED, __HIP_MEMORY_SCOPE_AGENT);
        barrier_lgkm();   // protect sM/sDst/sSrc before next gather
    }
}

// ---------------- fused prep: node_part (blocks<gridB) | hist | W23 (last block) ----------------
__global__ __launch_bounds__(256) void prep_kernel(
    const float* __restrict__ nf, const float* __restrict__ W1,
    const int* __restrict__ ei, int nE, int nN, int gridB,
    float* __restrict__ np, float* __restrict__ gz, int* __restrict__ counts,
    const float* __restrict__ W2, const float* __restrict__ W3, const float* __restrict__ b2,
    float* __restrict__ W23, float* __restrict__ b2w)
{
    __shared__ float sU[64][TN + 4];
    const int t = threadIdx.x;
    const int b = blockIdx.x;

    if (b >= gridB + HISTB) {
        // ---- W23 = W2 @ W3[64:128,:]; b2w = b2 @ W3[64:128,:] ----
        const int c = t & 63;
        const int kg = t >> 6;
        for (int k = kg * 16; k < kg * 16 + 16; ++k) {
            float s = 0.f;
            for (int m = 0; m < 64; ++m)
                s = fmaf(W2[k * 64 + m], W3[(64 + m) * 64 + c], s);
            W23[k * 64 + c] = s;
        }
        if (t < 64) {
            float s = 0.f;
            for (int m = 0; m < 64; ++m)
                s = fmaf(b2[m], W3[(64 + m) * 64 + t], s);
            b2w[t] = s;
        }
        return;
    }
    if (b >= gridB) {
        // ---- histogram of dst (counts pre-zeroed by memset) ----
        const int* dst = ei + nE;
        int e = (b - gridB) * 256 + t;
        const int stride = HISTB * 256;
        for (; e < nE; e += stride)
            atomicAdd(&counts[dst[e]], 1);
        return;
    }

    // ---- node_part: npart = nf @ W1[0:64,:]; zero gsum rows ----
    const int lane = t & 63;
    const int w = t >> 6;
    const int tb = b * TN;
    const int node = (tb + lane < nN) ? tb + lane : nN - 1;
    {
        const float4 z = make_float4(0.f, 0.f, 0.f, 0.f);
        const int base = tb * 64 + t * 4;
        #pragma unroll
        for (int pz = 0; pz < 4; ++pz) {
            const int idx = base + pz * 1024;
            if (idx < nN * 64) *(float4*)(gz + idx) = z;
        }
    }
    {
        const float4* nrow = (const float4*)(nf + (size_t)node * 64);
        F4 a0, a1, a2, a3;
        a0.v = nrow[w * 4 + 0];
        a1.v = nrow[w * 4 + 1];
        a2.v = nrow[w * 4 + 2];
        a3.v = nrow[w * 4 + 3];
        const int kb = w * 16;
        #pragma unroll
        for (int j = 0; j < 4; ++j) {
            sU[kb + 0  + j][lane] = a0.f[j];
            sU[kb + 4  + j][lane] = a1.f[j];
            sU[kb + 8  + j][lane] = a2.f[j];
            sU[kb + 12 + j][lane] = a3.f[j];
        }
    }
    barrier_lgkm();
    const int n0 = (t & 15) * 4;
    const int c0 = (t >> 4) * 4;
    float acc[4][4] = {};
    #pragma unroll 8
    for (int k = 0; k < 64; ++k) {
        F4 xv, wv;
        xv.v = *(const float4*)&sU[k][n0];
        wv.v = *(const float4*)(W1 + k * 64 + c0);
        #pragma unroll
        for (int i = 0; i < 4; ++i)
            #pragma unroll
            for (int j = 0; j < 4; ++j)
                acc[i][j] = fmaf(xv.f[i], wv.f[j], acc[i][j]);
    }
    #pragma unroll
    for (int i = 0; i < 4; ++i) {
        const int gnode = tb + n0 + i;
        if (gnode < nN) {
            F4 o;
            #pragma unroll
            for (int j = 0; j < 4; ++j) o.f[j] = acc[i][j];
            *(float4*)(np + (size_t)gnode * 64 + c0) = o.v;
        }
    }
}

// ---------------- scan chain ----------------
__global__ __launch_bounds__(256) void scan_local_kernel(const int* __restrict__ in,
                                                         int* __restrict__ out,
                                                         int* __restrict__ bsum, int n) {
    __shared__ int s[256];
    const int t = threadIdx.x;
    const int base = blockIdx.x * 2048 + t * 8;
    int v[8];
    #pragma unroll
    for (int i = 0; i < 8; ++i) v[i] = (base + i < n) ? in[base + i] : 0;
    int run = 0;
    #pragma unroll
    for (int i = 0; i < 8; ++i) { int c = v[i]; v[i] = run; run += c; }
    s[t] = run;
    __syncthreads();
    int x = run;
    for (int off = 1; off < 256; off <<= 1) {
        int y = (t >= off) ? s[t - off] : 0;
        __syncthreads();
        x += y; s[t] = x;
        __syncthreads();
    }
    const int texcl = x - run;
    if (t == 255) bsum[blockIdx.x] = x;
    #pragma unroll
    for (int i = 0; i < 8; ++i)
        if (base + i < n) out[base + i] = texcl + v[i];
}

__global__ void scan_bsums_kernel(int* bsum, int nb) {
    const int l = threadIdx.x;   // 64 threads
    if (nb <= 64) {
        int v = (l < nb) ? bsum[l] : 0;
        const int orig = v;
        for (int off = 1; off < 64; off <<= 1) {
            int y = __shfl_up(v, off, 64);
            if (l >= off) v += y;
        }
        if (l < nb) bsum[l] = v - orig;   // exclusive
    } else if (l == 0) {
        int run = 0;
        for (int b = 0; b < nb; ++b) { int tt = bsum[b]; bsum[b] = run; run += tt; }
    }
}

__global__ __launch_bounds__(256) void scan_add_kernel(int* __restrict__ offs,
                                                       const int* __restrict__ bsum,
                                                       int* __restrict__ cursor, int n) {
    const int base = blockIdx.x * 2048 + threadIdx.x * 8;
    const int add = bsum[blockIdx.x];
    #pragma unroll
    for (int i = 0; i < 8; ++i)
        if (base + i < n) { int v = offs[base + i] + add; offs[base + i] = v; cursor[base + i] = v; }
}

__global__ __launch_bounds__(256) void scatter_kernel(const int* __restrict__ ei,
                                                      int* __restrict__ cursor,
                                                      u64* __restrict__ esd, int nE) {
    int e = blockIdx.x * 256 + threadIdx.x;
    const int stride = gridDim.x * 256;
    for (; e < nE; e += stride) {
        const int s = ei[e];
        const int d = ei[nE + e];
        const int pos = atomicAdd(&cursor[d], 1);
        esd[pos] = (u64)(unsigned)s | ((u64)(unsigned)d << 17) | ((u64)(unsigned)e << 34);
    }
}

// ---------------- Fallback edge kernel (block-tile, full GEMM1+GEMM2+atomics) ----------------
__global__ __launch_bounds__(256, 4) void edge_mlp_kernel(
    const float* __restrict__ nf, const float* __restrict__ ef,
    const int* __restrict__ ei,
    const float* __restrict__ W1, const float* __restrict__ b1,
    const float* __restrict__ W2, const float* __restrict__ b2,
    float* agg, int nE, int nTiles)
{
    __shared__ float sX[80][TE + 4];
    __shared__ float sM[64][TE + 4];
    __shared__ int   sDst[TE];

    const int t    = threadIdx.x;
    const int lane = t & 63;
    const int w    = t >> 6;
    const int e0   = (t & 15) * 4;
    const int c0   = (t >> 4) * 4;
    F4 b1v, b2v;
    b1v.v = *(const float4*)(b1 + c0);
    b2v.v = *(const float4*)(b2 + c0);

    for (int tile = blockIdx.x; tile < nTiles; tile += gridDim.x) {
        const int gbase = tile * TE;
        {
            const int idx = gbase + lane;
            const int ge  = idx < nE ? idx : nE - 1;
            const int src = ei[ge];
            const int dstv = (idx < nE) ? ei[nE + ge] : -1;
            const float4* nrow = (const float4*)(nf + (size_t)src * 64);
            F4 a0, a1, a2, a3, ev;
            a0.v = nrow[w * 4 + 0];
            a1.v = nrow[w * 4 + 1];
            a2.v = nrow[w * 4 + 2];
            a3.v = nrow[w * 4 + 3];
            ev.v = *(const float4*)(ef + (size_t)ge * 16 + w * 4);
            const int kb = w * 16;
            #pragma unroll
            for (int j = 0; j < 4; ++j) {
                sX[kb + 0  + j][lane] = a0.f[j];
                sX[kb + 4  + j][lane] = a1.f[j];
                sX[kb + 8  + j][lane] = a2.f[j];
                sX[kb + 12 + j][lane] = a3.f[j];
                sX[64 + w * 4 + j][lane] = ev.f[j];
            }
            if (w == 0) sDst[lane] = dstv;
        }
        barrier_lgkm();

        float acc[4][4] = {};
        #pragma unroll 8
        for (int k = 0; k < 80; ++k) {
            F4 xv, wv;
            xv.v = *(const float4*)&sX[k][e0];
            wv.v = *(const float4*)(W1 + k * 64 + c0);
            #pragma unroll
            for (int i = 0; i < 4; ++i)
                #pragma unroll
                for (int j = 0; j < 4; ++j)
                    acc[i][j] = fmaf(xv.f[i], wv.f[j], acc[i][j]);
        }
        #pragma unroll
        for (int j = 0; j < 4; ++j) {
            F4 col;
            #pragma unroll
            for (int i = 0; i < 4; ++i)
                col.f[i] = gelu_f(acc[i][j] + b1v.f[j]);
            *(float4*)&sM[c0 + j][e0] = col.v;
        }
        barrier_lgkm();

        float acc2[4][4] = {};
        #pragma unroll 8
        for (int k = 0; k < 64; ++k) {
            F4 xv, wv;
            xv.v = *(const float4*)&sM[k][e0];
            wv.v = *(const float4*)(W2 + k * 64 + c0);
            #pragma unroll
            for (int i = 0; i < 4; ++i)
                #pragma unroll
                for (int j = 0; j < 4; ++j)
                    acc2[i][j] = fmaf(xv.f[i], wv.f[j], acc2[i][j]);
        }
        #pragma unroll
        for (int i = 0; i < 4; ++i) {
            if (gbase + e0 + i < nE) {
                float* arow = agg + (size_t)sDst[e0 + i] * 64 + c0;
                #pragma unroll
                for (int j = 0; j < 4; ++j)
                    __hip_atomic_fetch_add(arow + j, acc2[i][j] + b2v.f[j],
                                           __ATOMIC_RELAXED, __HIP_MEMORY_SCOPE_AGENT);
            }
        }
        barrier_lgkm();
    }
}

// ---------------- Kernel B: node update + LayerNorm + GELU + residual ----------------
__global__ __launch_bounds__(256) void node_update_kernel(
    const float* __restrict__ nf,
    const float* gsum,               // may alias out
    const float* __restrict__ W3,    // rows 0..63
    const float* __restrict__ wB,    // rows 64..127 (W23 or W3+4096)
    const float* __restrict__ b3,
    const float* __restrict__ cvec,  // b2w or null
    const int*   __restrict__ counts,// [N] or null
    const float* __restrict__ lns,
    const float* __restrict__ lnb,
    float* out, int nN)
{
    __shared__ float sW3[128][64];
    __shared__ float sU[128][TN + 4];
    __shared__ float sP1[16][TN];
    __shared__ float sP2[16][TN];
    __shared__ float sMu[TN];
    __shared__ float sRs[TN];

    const int t = threadIdx.x;
    for (int i = t * 4; i < 64 * 64; i += 1024)
        *(float4*)((float*)sW3 + i) = *(const float4*)(W3 + i);
    for (int i = t * 4; i < 64 * 64; i += 1024)
        *(float4*)((float*)sW3 + 4096 + i) = *(const float4*)(wB + i);

    const int lane = t & 63;
    const int w    = t >> 6;
    const int tb   = blockIdx.x * TN;
    const int node = tb + lane;
    const bool valid = node < nN;

    {
        const float* base = (w < 2) ? (nf   + (size_t)node * 64 + w * 32)
                                    : (gsum + (size_t)node * 64 + (w - 2) * 32);
        const int kb = (w < 2) ? (w * 32) : (64 + (w - 2) * 32);
        #pragma unroll
        for (int q = 0; q < 8; ++q) {
            F4 v;
            v.v = valid ? *(const float4*)(base + q * 4) : make_float4(0.f, 0.f, 0.f, 0.f);
            #pragma unroll
            for (int j = 0; j < 4; ++j)
                sU[kb + q * 4 + j][lane] = v.f[j];
        }
    }

    const int n0 = (t & 15) * 4;
    const int c0 = (t >> 4) * 4;
    F4 b3v, sv, bv, cv;
    b3v.v = *(const float4*)(b3  + c0);
    sv.v  = *(const float4*)(lns + c0);
    bv.v  = *(const float4*)(lnb + c0);
    if (cvec) cv.v = *(const float4*)(cvec + c0);
    __syncthreads();

    float acc[4][4] = {};
    #pragma unroll 8
    for (int k = 0; k < 128; ++k) {
        F4 xv, wv;
        xv.v = *(const float4*)&sU[k][n0];
        wv.v = *(const float4*)&sW3[k][c0];
        #pragma unroll
        for (int i = 0; i < 4; ++i)
            #pragma unroll
            for (int j = 0; j < 4; ++j)
                acc[i][j] = fmaf(xv.f[i], wv.f[j], acc[i][j]);
    }

    float h[4][4];
    #pragma unroll
    for (int i = 0; i < 4; ++i) {
        float cf = 0.f;
        if (counts) {
            const int gnode = tb + n0 + i;
            cf = (float)counts[gnode < nN ? gnode : nN - 1];
        }
        #pragma unroll
        for (int j = 0; j < 4; ++j) {
            float v = acc[i][j] + b3v.f[j];
            if (cvec) v = fmaf(cf, cv.f[j], v);
            h[i][j] = v;
        }
    }

    const int cg = t >> 4;
    #pragma unroll
    for (int i = 0; i < 4; ++i) {
        float s1 = h[i][0] + h[i][1] + h[i][2] + h[i][3];
        float s2 = h[i][0]*h[i][0] + h[i][1]*h[i][1] + h[i][2]*h[i][2] + h[i][3]*h[i][3];
        sP1[cg][n0 + i] = s1;
        sP2[cg][n0 + i] = s2;
    }
    __syncthreads();
    if (t < TN) {
        float m1 = 0.f, m2 = 0.f;
        #pragma unroll
        for (int g = 0; g < 16; ++g) { m1 += sP1[g][t]; m2 += sP2[g][t]; }
        float mu  = m1 * (1.f / 64.f);
        float var = m2 * (1.f / 64.f) - mu * mu;
        sMu[t] = mu;
        sRs[t] = rsqrtf(var + 1e-6f);
    }
    __syncthreads();

    #pragma unroll
    for (int i = 0; i < 4; ++i) {
        const int gnode = tb + n0 + i;
        const float mu = sMu[n0 + i];
        const float rs = sRs[n0 + i];
        if (gnode < nN) {
            #pragma unroll
            for (int j = 0; j < 4; ++j) {
                float xn = (h[i][j] - mu) * rs * sv.f[j] + bv.f[j];
                float r  = gelu_f(xn) + sU[c0 + j][n0 + i];
                out[(size_t)gnode * 64 + c0 + j] = r;
            }
        }
    }
}

extern "C" void kernel_launch(void* const* d_in, const int* in_sizes, int n_in,
                              void* d_out, int out_size, void* d_ws, size_t ws_size,
                              hipStream_t stream)
{
    const float* nf  = (const float*)d_in[0];
    const float* ef  = (const float*)d_in[1];
    const int*   ei  = (const int*)  d_in[2];
    const float* W1  = (const float*)d_in[3];
    const float* b1  = (const float*)d_in[4];
    const float* W2  = (const float*)d_in[5];
    const float* b2  = (const float*)d_in[6];
    const float* W3  = (const float*)d_in[7];
    const float* b3  = (const float*)d_in[8];
    const float* lns = (const float*)d_in[9];
    const float* lnb = (const float*)d_in[10];

    const int nN = in_sizes[0] / 64;
    const int nE = in_sizes[2] / 2;
    float* out = (float*)d_out;

    const int gridB = (nN + TN - 1) / TN;
    const int nTiles = (nE + TE - 1) / TE;

    // ws layout: CSR + folded weights -> nodePart -> gSum
    char* ws = (char*)d_ws;
    size_t off = 0;
    auto take = [&](size_t bytes) { void* p = ws + off; off = (off + bytes + 255) & ~(size_t)255; return p; };
    int*   counts = (int*)  take((size_t)nN * 4);
    int*   offs   = (int*)  take((size_t)nN * 4);
    int*   cursor = (int*)  take((size_t)nN * 4);
    int*   bsum   = (int*)  take(4096);
    u64*   esd    = (u64*)  take((size_t)nE * 8);
    float* W23    = (float*)take(64 * 64 * 4);
    float* b2w    = (float*)take(64 * 4);
    float* npart  = (float*)take((size_t)nN * 64 * 4);
    const size_t tier2End = off;
    float* gsumw  = (float*)take((size_t)nN * 64 * 4);
    const size_t tier3End = off;
    const size_t aggBytes = (size_t)nN * 64 * 4;
    const bool fitsPacked = (nN <= (1 << 17)) && (nE <= (1 << 21));

    if (ws_size >= tier2End && fitsPacked) {
        // ---- fast path: fused prep + scan + scatter + r13 edge kernel ----
        float* gsum = (ws_size >= tier3End) ? gsumw : out;  // aliasing out is safe (block-local RAW)
        const int nb = (nN + 2047) / 2048;
        hipMemsetAsync(counts, 0, (size_t)nN * 4, stream);
        hipLaunchKernelGGL(prep_kernel, dim3(gridB + HISTB + 1), dim3(256), 0, stream,
                           nf, W1, ei, nE, nN, gridB, npart, gsum, counts,
                           W2, W3, b2, W23, b2w);
        hipLaunchKernelGGL(scan_local_kernel, dim3(nb), dim3(256), 0, stream, counts, offs, bsum, nN);
        hipLaunchKernelGGL(scan_bsums_kernel, dim3(1), dim3(64), 0, stream, bsum, nb);
        hipLaunchKernelGGL(scan_add_kernel, dim3(nb), dim3(256), 0, stream, offs, bsum, cursor, nN);
        hipLaunchKernelGGL(scatter_kernel, dim3(2048), dim3(256), 0, stream, ei, cursor, esd, nE);

        const int gridE = nTiles < 1536 ? nTiles : 1536;   // 6 blocks/CU resident (22.5KB LDS)
        hipLaunchKernelGGL(edge_np_kernel, dim3(gridE), dim3(256), 0, stream,
                           ef, esd, npart, W1, b1, gsum, nE, nTiles);

        hipLaunchKernelGGL(node_update_kernel, dim3(gridB), dim3(256), 0, stream,
                           nf, gsum, W3, W23, b3, b2w, counts, lns, lnb, out, nN);
    } else {
        // ---- fallback: block-tile edge kernel with per-edge atomics ----
        const int gridA = nTiles < 1024 ? nTiles : 1024;
        float* agg = (ws_size >= aggBytes) ? (float*)d_ws : out;
        hipMemsetAsync(agg, 0, aggBytes, stream);
        hipLaunchKernelGGL(edge_mlp_kernel, dim3(gridA), dim3(256), 0, stream,
                           nf, ef, ei, W1, b1, W2, b2, agg, nE, nTiles);
        hipLaunchKernelGGL(node_update_kernel, dim3(gridB), dim3(256), 0, stream,
                           nf, agg, W3, W3 + 64 * 64, b3, (const float*)nullptr, (const int*)nullptr,
                           lns, lnb, out, nN);
    }
}